// Round 16
// baseline (131.279 us; speedup 1.0000x reference)
//
#include <hip/hip_runtime.h>
#include <hip/hip_bf16.h>
#include <stdint.h>

typedef uint16_t u16;
typedef uint32_t u32;
typedef __attribute__((ext_vector_type(8))) short short8;   // 8 x bf16 (MFMA A/B frag)
typedef __attribute__((ext_vector_type(4))) float f32x4;    // MFMA C/D frag

#define LOG2E 1.44269504088896340736f

__device__ __forceinline__ u16 f2bf(float f) {
    u32 u = __builtin_bit_cast(u32, f);
    return (u16)((u + 0x7fffu + ((u >> 16) & 1u)) >> 16);   // RNE
}
__device__ __forceinline__ float bf2f(u16 h) {
    u32 u = ((u32)h) << 16;
    return __builtin_bit_cast(float, u);
}
__device__ __forceinline__ u32 pack_bf16(float lo, float hi) {
    return (u32)f2bf(lo) | ((u32)f2bf(hi) << 16);   // RNE pack
}
// fast pack for softmax P (values are exp2 outputs: finite, positive; round-half-up is fine)
__device__ __forceinline__ u32 pack_bf16_fast(float lo, float hi) {
    u32 a = __builtin_bit_cast(u32, lo) + 0x8000u;
    u32 b = __builtin_bit_cast(u32, hi) + 0x8000u;
    return (a >> 16) | (b & 0xffff0000u);
}

// ------------------- weights: transpose + bf16 (+ fold 0.125*log2e into Wk,bk -> log2-domain scores)
__global__ void wt_kernel(const float* __restrict__ Wq, const float* __restrict__ Wk,
                          const float* __restrict__ Wv, const float* __restrict__ Wo,
                          const float* __restrict__ bk, u16* __restrict__ WT,
                          float* __restrict__ bks) {
    const int wsel = blockIdx.y, k = blockIdx.x, n = threadIdx.x;
    const float* W = (wsel == 0) ? Wq : (wsel == 1) ? Wk : (wsel == 2) ? Wv : Wo;
    const float scale = (wsel == 1) ? (0.125f * LOG2E) : 1.0f;
    WT[(size_t)wsel * 65536 + (size_t)n * 256 + k] = f2bf(W[(size_t)k * 256 + n] * scale);
    if (wsel == 1 && k == 0) bks[n] = bk[n] * (0.125f * LOG2E);
}

// ---------------------------------------------------------------- projection GEMM (f32 in, bf16 out)
// R12-verified: 64x256 tile, A read once, 4 waves, BK=64, XOR-swizzled LDS. Grid (256, 3).
__global__ __launch_bounds__(256)
void proj_kernel(const float* __restrict__ Qf, const float* __restrict__ Kf,
                 const u16* __restrict__ WT, const float* __restrict__ bq,
                 const float* __restrict__ bks, const float* __restrict__ bvv,
                 u16* __restrict__ qb, u16* __restrict__ kbuf, u16* __restrict__ vbuf) {
    const int z = blockIdx.y;
    const float* Af = (z == 0) ? Qf : Kf;
    const u16* BT = WT + z * 65536;
    const float* bias = (z == 0) ? bq : (z == 1) ? bks : bvv;
    u16* out = (z == 0) ? qb : (z == 1) ? kbuf : vbuf;

    __shared__ u16 As[64 * 64];    // 8 KB
    __shared__ u16 Bs[256 * 64];   // 32 KB
    const int tid = threadIdx.x;
    const int w = tid >> 6, lane = tid & 63;
    const int g = lane >> 4, lo = lane & 15;
    const int rowB = blockIdx.x * 64;
    const int wc = w * 64;

    const f32x4 fz = {0.f, 0.f, 0.f, 0.f};
    f32x4 acc[4][4];
#pragma unroll
    for (int m = 0; m < 4; ++m)
#pragma unroll
        for (int n = 0; n < 4; ++n) acc[m][n] = fz;

    const int arow = tid & 63, aqtr = tid >> 6;

#pragma unroll 1
    for (int kt = 0; kt < 4; ++kt) {
        const int k0 = kt * 64;
        __syncthreads();
        {
            const float* ga = Af + (size_t)(rowB + arow) * 256 + k0 + aqtr * 16;
            float4 x0 = *(const float4*)ga;
            float4 x1 = *(const float4*)(ga + 4);
            float4 x2 = *(const float4*)(ga + 8);
            float4 x3 = *(const float4*)(ga + 12);
            uint4 pa0, pa1;
            pa0.x = pack_bf16(x0.x, x0.y); pa0.y = pack_bf16(x0.z, x0.w);
            pa0.z = pack_bf16(x1.x, x1.y); pa0.w = pack_bf16(x1.z, x1.w);
            pa1.x = pack_bf16(x2.x, x2.y); pa1.y = pack_bf16(x2.z, x2.w);
            pa1.z = pack_bf16(x3.x, x3.y); pa1.w = pack_bf16(x3.z, x3.w);
            const u32 swA = (u32)((arow & 7) << 4);
            const u32 baA = (u32)(arow * 128 + aqtr * 32);
            *(uint4*)((char*)As + ((baA) ^ swA))      = pa0;
            *(uint4*)((char*)As + ((baA + 16) ^ swA)) = pa1;
            const u16* gb = BT + (size_t)tid * 256 + k0;
            const u32 swB = (u32)((tid & 7) << 4);
            const u32 baB = (u32)(tid * 128);
#pragma unroll
            for (int j = 0; j < 8; ++j) {
                uint4 bj = *(const uint4*)(gb + j * 8);
                *(uint4*)((char*)Bs + ((baB + j * 16) ^ swB)) = bj;
            }
        }
        __syncthreads();
#pragma unroll
        for (int c = 0; c < 2; ++c) {
            short8 af[4], bfr[4];
#pragma unroll
            for (int m = 0; m < 4; ++m) {
                const int row = m * 16 + lo;
                const u32 addr = (u32)(row * 128 + c * 64 + g * 16) ^ (u32)((row & 7) << 4);
                af[m] = *(const short8*)((char*)As + addr);
            }
#pragma unroll
            for (int n = 0; n < 4; ++n) {
                const int row = wc + n * 16 + lo;
                const u32 addr = (u32)(row * 128 + c * 64 + g * 16) ^ (u32)((row & 7) << 4);
                bfr[n] = *(const short8*)((char*)Bs + addr);
            }
#pragma unroll
            for (int m = 0; m < 4; ++m)
#pragma unroll
                for (int n = 0; n < 4; ++n)
                    acc[m][n] = __builtin_amdgcn_mfma_f32_16x16x32_bf16(af[m], bfr[n], acc[m][n], 0, 0, 0);
        }
    }

    float bv[4];
#pragma unroll
    for (int n = 0; n < 4; ++n) bv[n] = bias[wc + n * 16 + lo];
#pragma unroll
    for (int m = 0; m < 4; ++m)
#pragma unroll
        for (int r = 0; r < 4; ++r) {
            const size_t row = (size_t)(rowB + m * 16 + g * 4 + r);
#pragma unroll
            for (int n = 0; n < 4; ++n)
                out[row * 256 + wc + n * 16 + lo] = f2bf(acc[m][n][r] + bv[n]);
        }
}

// ---------------------------------------------------------------- flash attention + q-residual
// 4 waves x 16 q-rows (64 q/block), grid 1024 -> 4 blocks/CU (16 waves/CU), 4-wave barrier groups.
// Staging: every thread stages K (2 uint4) AND V-transpose (2 uint4 repack) — R7-verified pattern.
// dbuf K/V, t+2 prefetch, setprio, ones-MFMA l, log2-softmax, defer-max, bf16 out.
// XCD decode: all 32 member-blocks of one (b,h) on one XCD (bid = u*256 + m*8 + xcd).
__global__ __launch_bounds__(256, 4)
void attn_kernel(const u16* __restrict__ qb, const u16* __restrict__ kb,
                 const u16* __restrict__ vb, u16* __restrict__ Ob) {
    __shared__ u16 Klds[2 * 64 * 64];   // 16 KB
    __shared__ u16 Vtlds[2 * 64 * 64];  // 16 KB
    __shared__ u16 Plds[4 * 16 * 64];   // 8 KB
    const int tid = threadIdx.x;
    const int w = tid >> 6, lane = tid & 63;
    const int g = lane >> 4, lo = lane & 15;
    const int bid = blockIdx.x;
    const int xcd = bid & 7;
    const int member = (bid >> 3) & 31;
    const int grp = ((bid >> 8) << 3) | xcd;    // [0,32): (b,h) group
    const int q0 = member * 64;
    const int h = grp & 3, b = grp >> 2;
    const size_t hbase = (size_t)b * 2048 * 256 + (size_t)h * 64;

    short8 qf[2];
#pragma unroll
    for (int c = 0; c < 2; ++c) {
        const size_t row = (size_t)(q0 + w * 16 + lo);
        qf[c] = *(const short8*)&qb[hbase + row * 256 + c * 32 + g * 8];
    }
    const short8 vones = {0x3F80, 0x3F80, 0x3F80, 0x3F80, 0x3F80, 0x3F80, 0x3F80, 0x3F80};

    const f32x4 fz = {0.f, 0.f, 0.f, 0.f};
    f32x4 oacc[4];
#pragma unroll
    for (int n = 0; n < 4; ++n) oacc[n] = fz;
    f32x4 l_acc = fz;
    float m_run = -1e30f;

    char* Pb = (char*)Plds + w * 2048;

    // staging: every thread stages K (2 x uint4) and V-transpose (2 x uint4 repacked) — R7 pattern
    const int skey = tid & 63, sseg = tid >> 6;
    const int vkey = (tid & 31) * 2, vd0 = (tid >> 5) * 8;
    const u16* gk = &kb[hbase + (size_t)skey * 256 + sseg * 16];
    const u16* gv = &vb[hbase + (size_t)vkey * 256 + vd0];

    uint4 k0s, k1s, v0s, v1s;
    auto load_tile = [&](int kt) {
        const u16* pk = gk + (size_t)kt * 16384;
        k0s = *(const uint4*)pk;
        k1s = *(const uint4*)(pk + 8);
        const u16* pv = gv + (size_t)kt * 16384;
        v0s = *(const uint4*)pv;
        v1s = *(const uint4*)(pv + 256);
    };
    auto write_tile = [&](int sel) {
        char* Kb_ = (char*)Klds + sel * 8192;
        const u32 sw = (u32)((skey & 7) << 4);
        const u32 ba = (u32)(skey * 128 + sseg * 32);
        *(uint4*)(Kb_ + ((ba) ^ sw)) = k0s;
        *(uint4*)(Kb_ + ((ba + 16) ^ sw)) = k1s;
        char* Vb_ = (char*)Vtlds + sel * 8192;
        union { uint4 v; u16 hh[8]; } a0, a1;
        a0.v = v0s; a1.v = v1s;
#pragma unroll
        for (int i = 0; i < 8; ++i) {
            const int d = vd0 + i;
            const u32 addr = (u32)(d * 128 + vkey * 2) ^ (u32)((d & 7) << 4);
            *(u32*)(Vb_ + addr) = (u32)a0.hh[i] | ((u32)a1.hh[i] << 16);
        }
    };

    load_tile(0);
    write_tile(0);
    load_tile(1);
    __syncthreads();

#pragma unroll 1
    for (int kt = 0; kt < 32; ++kt) {
        const int cur = kt & 1;
        char* Klb = (char*)Klds + cur * 8192;
        char* Vtb = (char*)Vtlds + cur * 8192;

        // QK^T (swapped)
        f32x4 sc[4];
#pragma unroll
        for (int km = 0; km < 4; ++km) sc[km] = fz;
        __builtin_amdgcn_s_setprio(1);
#pragma unroll
        for (int c = 0; c < 2; ++c)
#pragma unroll
            for (int km = 0; km < 4; ++km) {
                const int key = km * 16 + lo;
                const u32 addr = (u32)(key * 128 + c * 64 + g * 16) ^ (u32)((key & 7) << 4);
                const short8 kf = *(const short8*)(Klb + addr);
                sc[km] = __builtin_amdgcn_mfma_f32_16x16x32_bf16(kf, qf[c], sc[km], 0, 0, 0);
            }
        __builtin_amdgcn_s_setprio(0);

        // online softmax (per q = lo), deferred-max
        float mt = -1e30f;
#pragma unroll
        for (int km = 0; km < 4; ++km)
#pragma unroll
            for (int r = 0; r < 4; ++r) mt = fmaxf(mt, sc[km][r]);
        mt = fmaxf(mt, __shfl_xor(mt, 16));
        mt = fmaxf(mt, __shfl_xor(mt, 32));
        if (!__all(mt <= m_run + 11.5f)) {
            const float mnew = fmaxf(m_run, mt);
            const float alpha = __builtin_amdgcn_exp2f(m_run - mnew);
#pragma unroll
            for (int r = 0; r < 4; ++r) {
                const float a = __shfl(alpha, (lane & 48) | (g * 4 + r));
                l_acc[r] *= a;
#pragma unroll
                for (int n = 0; n < 4; ++n) oacc[n][r] *= a;
            }
            m_run = mnew;
        }
#pragma unroll
        for (int km = 0; km < 4; ++km)
#pragma unroll
            for (int r = 0; r < 4; ++r)
                sc[km][r] = __builtin_amdgcn_exp2f(sc[km][r] - m_run);

        // P^T -> P_lds
        {
            const u32 sw = (u32)((lo & 7) << 4);
#pragma unroll
            for (int km = 0; km < 4; ++km) {
                uint2 val;
                val.x = pack_bf16_fast(sc[km][0], sc[km][1]);
                val.y = pack_bf16_fast(sc[km][2], sc[km][3]);
                const u32 addr = (u32)(lo * 128 + km * 32 + g * 8) ^ sw;
                *(uint2*)(Pb + addr) = val;
            }
        }

        // PV + ones-column l
        __builtin_amdgcn_s_setprio(1);
#pragma unroll
        for (int c = 0; c < 2; ++c) {
            const u32 paddr = (u32)(lo * 128 + c * 64 + g * 16) ^ (u32)((lo & 7) << 4);
            const short8 pf = *(const short8*)(Pb + paddr);
#pragma unroll
            for (int n = 0; n < 4; ++n) {
                const int d = n * 16 + lo;
                const u32 addr = (u32)(d * 128 + c * 64 + g * 16) ^ (u32)((d & 7) << 4);
                const short8 vf = *(const short8*)(Vtb + addr);
                oacc[n] = __builtin_amdgcn_mfma_f32_16x16x32_bf16(pf, vf, oacc[n], 0, 0, 0);
            }
            l_acc = __builtin_amdgcn_mfma_f32_16x16x32_bf16(pf, vones, l_acc, 0, 0, 0);
        }
        __builtin_amdgcn_s_setprio(0);

        if (kt < 31) write_tile(cur ^ 1);
        if (kt < 30) load_tile(kt + 2);
        __syncthreads();
    }

    // finalize: O = bf16(q + oacc / l)
#pragma unroll
    for (int r = 0; r < 4; ++r) {
        const float li = 1.0f / l_acc[r];
        const size_t row = (size_t)(q0 + w * 16 + g * 4 + r);
#pragma unroll
        for (int n = 0; n < 4; ++n) {
            const int d = n * 16 + lo;
            const size_t idx = hbase + row * 256 + d;
            Ob[idx] = f2bf(oacc[n][r] * li + bf2f(qb[idx]));
        }
    }
}

// ---------------------------------------------------------------- fused tail: LN0 + MLP + LN1
// R15-verified 32-row structure. Grid 512 (2 blocks/CU), LDS 48 KB (Xs 16 KB + Bs 32 KB).
__global__ __launch_bounds__(256)
void tail_kernel(const u16* __restrict__ Ob, const u16* __restrict__ BT,
                 const float* __restrict__ bo, const float* __restrict__ g0,
                 const float* __restrict__ be0, const float* __restrict__ g1,
                 const float* __restrict__ be1, float* __restrict__ out) {
    __shared__ char lds[49152];          // Xs 16 KB @0 (row stride 512B), Bs 32 KB @16384
    char* Xs = lds;
    u16* Bs = (u16*)(lds + 16384);
    const int tid = threadIdx.x;
    const int w = tid >> 6, lane = tid & 63;
    const int g = lane >> 4, lo = lane & 15;
    const int rowB = blockIdx.x * 32;
    const int wc = w * 64;

    const int lrow = tid >> 3, lseg = tid & 7;   // 32 rows x 8 segs of 32 cols
    const u32 lsw = (u32)((lrow & 7) << 4);

    // ---------------- hoisted kt=0 Bs staging (overlaps B global-load latency with LN0)
    {
        const u16* gb = BT + (size_t)tid * 256;
        const u32 swB = (u32)((tid & 7) << 4);
        const u32 baB = (u32)(tid * 128);
#pragma unroll
        for (int j = 0; j < 8; ++j) {
            uint4 bj = *(const uint4*)(gb + j * 8);
            *(uint4*)((char*)Bs + ((baB + j * 16) ^ swB)) = bj;
        }
    }

    // ---------------- phase 0: LN0 -> Xs
    {
        const size_t grow = (size_t)(rowB + lrow);
        const u16* src = Ob + grow * 256 + lseg * 32;
        uint4 r4[4];
#pragma unroll
        for (int j = 0; j < 4; ++j) r4[j] = *(const uint4*)(src + j * 8);
        float s = 0.f, q = 0.f;
#pragma unroll
        for (int j = 0; j < 4; ++j) {
            const u32 uu[4] = {r4[j].x, r4[j].y, r4[j].z, r4[j].w};
#pragma unroll
            for (int e = 0; e < 4; ++e) {
                const float f0 = bf2f((u16)(uu[e] & 0xffff));
                const float f1 = bf2f((u16)(uu[e] >> 16));
                s += f0 + f1;
                q += f0 * f0 + f1 * f1;
            }
        }
        s += __shfl_xor(s, 1); q += __shfl_xor(q, 1);
        s += __shfl_xor(s, 2); q += __shfl_xor(q, 2);
        s += __shfl_xor(s, 4); q += __shfl_xor(q, 4);
        const float mu = s * (1.f / 256.f);
        const float var = q * (1.f / 256.f) - mu * mu;
        const float rstd = rsqrtf(var + 1e-5f);
        const float* gp = g0 + lseg * 32;
        const float* bp = be0 + lseg * 32;
#pragma unroll
        for (int j = 0; j < 4; ++j) {
            const u32 uu[4] = {r4[j].x, r4[j].y, r4[j].z, r4[j].w};
            float4 gv0 = *(const float4*)(gp + j * 8);
            float4 gv1 = *(const float4*)(gp + j * 8 + 4);
            float4 bb0 = *(const float4*)(bp + j * 8);
            float4 bb1 = *(const float4*)(bp + j * 8 + 4);
            uint4 o;
            o.x = pack_bf16((bf2f((u16)(uu[0] & 0xffff)) - mu) * rstd * gv0.x + bb0.x,
                            (bf2f((u16)(uu[0] >> 16))    - mu) * rstd * gv0.y + bb0.y);
            o.y = pack_bf16((bf2f((u16)(uu[1] & 0xffff)) - mu) * rstd * gv0.z + bb0.z,
                            (bf2f((u16)(uu[1] >> 16))    - mu) * rstd * gv0.w + bb0.w);
            o.z = pack_bf16((bf2f((u16)(uu[2] & 0xffff)) - mu) * rstd * gv1.x + bb1.x,
                            (bf2f((u16)(uu[2] >> 16))    - mu) * rstd * gv1.y + bb1.y);
            o.w = pack_bf16((bf2f((u16)(uu[3] & 0xffff)) - mu) * rstd * gv1.z + bb1.z,
                            (bf2f((u16)(uu[3] >> 16))    - mu) * rstd * gv1.w + bb1.w);
            const u32 addr = (u32)(lrow * 512 + lseg * 64 + j * 16) ^ lsw;
            *(uint4*)(Xs + addr) = o;
        }
    }
    __syncthreads();   // covers BOTH hoisted Bs-stage writes and phase-0 Xs writes

    // ---------------- GEMM: acc = X @ Wo (A from Xs; Bs staged per K-tile, kt=0 pre-staged)
    const f32x4 fz = {0.f, 0.f, 0.f, 0.f};
    f32x4 acc[2][4];
#pragma unroll
    for (int m = 0; m < 2; ++m)
#pragma unroll
        for (int n = 0; n < 4; ++n) acc[m][n] = fz;

#pragma unroll 1
    for (int kt = 0; kt < 4; ++kt) {
        if (kt) {
            __syncthreads();   // all waves done reading Bs(kt-1)
            const u16* gb = BT + (size_t)tid * 256 + kt * 64;
            const u32 swB = (u32)((tid & 7) << 4);
            const u32 baB = (u32)(tid * 128);
#pragma unroll
            for (int j = 0; j < 8; ++j) {
                uint4 bj = *(const uint4*)(gb + j * 8);
                *(uint4*)((char*)Bs + ((baB + j * 16) ^ swB)) = bj;
            }
            __syncthreads();
        }
#pragma unroll
        for (int c = 0; c < 2; ++c) {
            short8 af[2], bfr[4];
#pragma unroll
            for (int m = 0; m < 2; ++m) {
                const int row = m * 16 + lo;
                const u32 addr = (u32)(row * 512 + kt * 128 + c * 64 + g * 16) ^ (u32)((row & 7) << 4);
                af[m] = *(const short8*)(Xs + addr);
            }
#pragma unroll
            for (int n = 0; n < 4; ++n) {
                const int row = wc + n * 16 + lo;
                const u32 addr = (u32)(row * 128 + c * 64 + g * 16) ^ (u32)((row & 7) << 4);
                bfr[n] = *(const short8*)((char*)Bs + addr);
            }
#pragma unroll
            for (int m = 0; m < 2; ++m)
#pragma unroll
                for (int n = 0; n < 4; ++n)
                    acc[m][n] = __builtin_amdgcn_mfma_f32_16x16x32_bf16(af[m], bfr[n], acc[m][n], 0, 0, 0);
        }
    }

    float bv[4];
#pragma unroll
    for (int n = 0; n < 4; ++n) bv[n] = bo[wc + n * 16 + lo];

    __syncthreads();   // ALL af reads of Xs complete before y overwrites

    // ---------------- epilogue: y = X + relu(acc+bias), element-wise overwrite of Xs
#pragma unroll
    for (int m = 0; m < 2; ++m)
#pragma unroll
        for (int r = 0; r < 4; ++r) {
            const int row_l = m * 16 + g * 4 + r;
            const u32 sw = (u32)((row_l & 7) << 4);
#pragma unroll
            for (int n = 0; n < 4; ++n) {
                const int col = wc + n * 16 + lo;
                const u32 badr = (u32)(row_l * 512 + col * 2);
                char* p = Xs + ((badr & ~15u) ^ sw) + (badr & 15u);
                const float resid = bf2f(*(u16*)p);
                *(u16*)p = f2bf(resid + fmaxf(acc[m][n][r] + bv[n], 0.f));
            }
        }
    __syncthreads();

    // ---------------- phase 2: LN1 over Xs -> d_out (two passes)
    {
        const u32 rbase = (u32)(lrow * 512 + lseg * 64);
        float s = 0.f, q = 0.f;
#pragma unroll
        for (int j = 0; j < 4; ++j) {
            uint4 v4 = *(const uint4*)(Xs + ((rbase + j * 16) ^ lsw));
            const u32 uu[4] = {v4.x, v4.y, v4.z, v4.w};
#pragma unroll
            for (int e = 0; e < 4; ++e) {
                const float f0 = bf2f((u16)(uu[e] & 0xffff));
                const float f1 = bf2f((u16)(uu[e] >> 16));
                s += f0 + f1;
                q += f0 * f0 + f1 * f1;
            }
        }
        s += __shfl_xor(s, 1); q += __shfl_xor(q, 1);
        s += __shfl_xor(s, 2); q += __shfl_xor(q, 2);
        s += __shfl_xor(s, 4); q += __shfl_xor(q, 4);
        const float mu = s * (1.f / 256.f);
        const float var = q * (1.f / 256.f) - mu * mu;
        const float rstd = rsqrtf(var + 1e-5f);
        const size_t grow = (size_t)(rowB + lrow);
        float* op = out + grow * 256 + lseg * 32;
        const float* gp = g1 + lseg * 32;
        const float* bp = be1 + lseg * 32;
#pragma unroll
        for (int j = 0; j < 4; ++j) {
            uint4 v4 = *(const uint4*)(Xs + ((rbase + j * 16) ^ lsw));
            const u32 uu[4] = {v4.x, v4.y, v4.z, v4.w};
#pragma unroll
            for (int e = 0; e < 2; ++e) {
                float4 gv = *(const float4*)(gp + j * 8 + e * 4);
                float4 bb = *(const float4*)(bp + j * 8 + e * 4);
                float4 o4;
                o4.x = (bf2f((u16)(uu[e * 2]     & 0xffff)) - mu) * rstd * gv.x + bb.x;
                o4.y = (bf2f((u16)(uu[e * 2]     >> 16))    - mu) * rstd * gv.y + bb.y;
                o4.z = (bf2f((u16)(uu[e * 2 + 1] & 0xffff)) - mu) * rstd * gv.z + bb.z;
                o4.w = (bf2f((u16)(uu[e * 2 + 1] >> 16))    - mu) * rstd * gv.w + bb.w;
                *(float4*)(op + j * 8 + e * 4) = o4;
            }
        }
    }
}

// ----------------------------------------------------------------------------------------------
// Workspace: qb 8MB | kbuf 8MB | vbuf 8MB | WT 0.5MB | bks | Ob16 8MB — ~32.75MB. 4 launches.
extern "C" void kernel_launch(void* const* d_in, const int* in_sizes, int n_in,
                              void* d_out, int out_size, void* d_ws, size_t ws_size,
                              hipStream_t stream) {
    const float* Q  = (const float*)d_in[0];
    const float* K  = (const float*)d_in[1];
    const float* Wq = (const float*)d_in[2];
    const float* bq = (const float*)d_in[3];
    const float* Wk = (const float*)d_in[4];
    const float* bk = (const float*)d_in[5];
    const float* Wv = (const float*)d_in[6];
    const float* bv = (const float*)d_in[7];
    const float* Wo = (const float*)d_in[8];
    const float* bo = (const float*)d_in[9];
    const float* g0 = (const float*)d_in[10];
    const float* be0 = (const float*)d_in[11];
    const float* g1 = (const float*)d_in[12];
    const float* be1 = (const float*)d_in[13];
    float* out = (float*)d_out;

    const size_t NE = (size_t)8 * 2048 * 256;  // 4,194,304
    char* ws = (char*)d_ws;
    size_t off = 0;
    auto alloc = [&](size_t bytes) { char* p = ws + off; off += (bytes + 255) & ~(size_t)255; return p; };
    u16* qb   = (u16*)alloc(NE * 2);
    u16* kbuf = (u16*)alloc(NE * 2);
    u16* vbuf = (u16*)alloc(NE * 2);
    u16* WT   = (u16*)alloc(4 * 65536 * 2);
    float* bks = (float*)alloc(256 * 4);
    u16* Ob16 = (u16*)alloc(NE * 2);

    wt_kernel<<<dim3(256, 4), 256, 0, stream>>>(Wq, Wk, Wv, Wo, bk, WT, bks);

    proj_kernel<<<dim3(256, 3), 256, 0, stream>>>(Q, K, WT, bq, bks, bv, qb, kbuf, vbuf);

    attn_kernel<<<1024, 256, 0, stream>>>(qb, kbuf, vbuf, Ob16);

    tail_kernel<<<512, 256, 0, stream>>>(Ob16, WT + 3 * 65536, bo, g0, be0, g1, be1, out);
}

// Round 17
// 112.800 us; speedup vs baseline: 1.1638x; 1.1638x over previous
//
#include <hip/hip_runtime.h>
#include <hip/hip_bf16.h>
#include <stdint.h>

typedef uint16_t u16;
typedef uint32_t u32;
typedef __attribute__((ext_vector_type(8))) short short8;   // 8 x bf16 (MFMA A/B frag)
typedef __attribute__((ext_vector_type(4))) float f32x4;    // MFMA C/D frag

#define LOG2E 1.44269504088896340736f

__device__ __forceinline__ u16 f2bf(float f) {
    u32 u = __builtin_bit_cast(u32, f);
    return (u16)((u + 0x7fffu + ((u >> 16) & 1u)) >> 16);   // RNE
}
__device__ __forceinline__ float bf2f(u16 h) {
    u32 u = ((u32)h) << 16;
    return __builtin_bit_cast(float, u);
}
__device__ __forceinline__ u32 pack_bf16(float lo, float hi) {
    return (u32)f2bf(lo) | ((u32)f2bf(hi) << 16);   // RNE pack
}
// fast pack for softmax P (values are exp2 outputs: finite, positive; round-half-up is fine)
__device__ __forceinline__ u32 pack_bf16_fast(float lo, float hi) {
    u32 a = __builtin_bit_cast(u32, lo) + 0x8000u;
    u32 b = __builtin_bit_cast(u32, hi) + 0x8000u;
    return (a >> 16) | (b & 0xffff0000u);
}

// ------------------- weights: transpose + bf16 (+ fold 0.125*log2e into Wk,bk -> log2-domain scores)
__global__ void wt_kernel(const float* __restrict__ Wq, const float* __restrict__ Wk,
                          const float* __restrict__ Wv, const float* __restrict__ Wo,
                          const float* __restrict__ bk, u16* __restrict__ WT,
                          float* __restrict__ bks) {
    const int wsel = blockIdx.y, k = blockIdx.x, n = threadIdx.x;
    const float* W = (wsel == 0) ? Wq : (wsel == 1) ? Wk : (wsel == 2) ? Wv : Wo;
    const float scale = (wsel == 1) ? (0.125f * LOG2E) : 1.0f;
    WT[(size_t)wsel * 65536 + (size_t)n * 256 + k] = f2bf(W[(size_t)k * 256 + n] * scale);
    if (wsel == 1 && k == 0) bks[n] = bk[n] * (0.125f * LOG2E);
}

// ---------------------------------------------------------------- projection GEMM (f32 in, bf16 out)
// R12-verified: 64x256 tile, A read once, 4 waves, BK=64, XOR-swizzled LDS. Grid (256, 3).
__global__ __launch_bounds__(256)
void proj_kernel(const float* __restrict__ Qf, const float* __restrict__ Kf,
                 const u16* __restrict__ WT, const float* __restrict__ bq,
                 const float* __restrict__ bks, const float* __restrict__ bvv,
                 u16* __restrict__ qb, u16* __restrict__ kbuf, u16* __restrict__ vbuf) {
    const int z = blockIdx.y;
    const float* Af = (z == 0) ? Qf : Kf;
    const u16* BT = WT + z * 65536;
    const float* bias = (z == 0) ? bq : (z == 1) ? bks : bvv;
    u16* out = (z == 0) ? qb : (z == 1) ? kbuf : vbuf;

    __shared__ u16 As[64 * 64];    // 8 KB
    __shared__ u16 Bs[256 * 64];   // 32 KB
    const int tid = threadIdx.x;
    const int w = tid >> 6, lane = tid & 63;
    const int g = lane >> 4, lo = lane & 15;
    const int rowB = blockIdx.x * 64;
    const int wc = w * 64;

    const f32x4 fz = {0.f, 0.f, 0.f, 0.f};
    f32x4 acc[4][4];
#pragma unroll
    for (int m = 0; m < 4; ++m)
#pragma unroll
        for (int n = 0; n < 4; ++n) acc[m][n] = fz;

    const int arow = tid & 63, aqtr = tid >> 6;

#pragma unroll 1
    for (int kt = 0; kt < 4; ++kt) {
        const int k0 = kt * 64;
        __syncthreads();
        {
            const float* ga = Af + (size_t)(rowB + arow) * 256 + k0 + aqtr * 16;
            float4 x0 = *(const float4*)ga;
            float4 x1 = *(const float4*)(ga + 4);
            float4 x2 = *(const float4*)(ga + 8);
            float4 x3 = *(const float4*)(ga + 12);
            uint4 pa0, pa1;
            pa0.x = pack_bf16(x0.x, x0.y); pa0.y = pack_bf16(x0.z, x0.w);
            pa0.z = pack_bf16(x1.x, x1.y); pa0.w = pack_bf16(x1.z, x1.w);
            pa1.x = pack_bf16(x2.x, x2.y); pa1.y = pack_bf16(x2.z, x2.w);
            pa1.z = pack_bf16(x3.x, x3.y); pa1.w = pack_bf16(x3.z, x3.w);
            const u32 swA = (u32)((arow & 7) << 4);
            const u32 baA = (u32)(arow * 128 + aqtr * 32);
            *(uint4*)((char*)As + ((baA) ^ swA))      = pa0;
            *(uint4*)((char*)As + ((baA + 16) ^ swA)) = pa1;
            const u16* gb = BT + (size_t)tid * 256 + k0;
            const u32 swB = (u32)((tid & 7) << 4);
            const u32 baB = (u32)(tid * 128);
#pragma unroll
            for (int j = 0; j < 8; ++j) {
                uint4 bj = *(const uint4*)(gb + j * 8);
                *(uint4*)((char*)Bs + ((baB + j * 16) ^ swB)) = bj;
            }
        }
        __syncthreads();
#pragma unroll
        for (int c = 0; c < 2; ++c) {
            short8 af[4], bfr[4];
#pragma unroll
            for (int m = 0; m < 4; ++m) {
                const int row = m * 16 + lo;
                const u32 addr = (u32)(row * 128 + c * 64 + g * 16) ^ (u32)((row & 7) << 4);
                af[m] = *(const short8*)((char*)As + addr);
            }
#pragma unroll
            for (int n = 0; n < 4; ++n) {
                const int row = wc + n * 16 + lo;
                const u32 addr = (u32)(row * 128 + c * 64 + g * 16) ^ (u32)((row & 7) << 4);
                bfr[n] = *(const short8*)((char*)Bs + addr);
            }
#pragma unroll
            for (int m = 0; m < 4; ++m)
#pragma unroll
                for (int n = 0; n < 4; ++n)
                    acc[m][n] = __builtin_amdgcn_mfma_f32_16x16x32_bf16(af[m], bfr[n], acc[m][n], 0, 0, 0);
        }
    }

    float bv[4];
#pragma unroll
    for (int n = 0; n < 4; ++n) bv[n] = bias[wc + n * 16 + lo];
#pragma unroll
    for (int m = 0; m < 4; ++m)
#pragma unroll
        for (int r = 0; r < 4; ++r) {
            const size_t row = (size_t)(rowB + m * 16 + g * 4 + r);
#pragma unroll
            for (int n = 0; n < 4; ++n)
                out[row * 256 + wc + n * 16 + lo] = f2bf(acc[m][n][r] + bv[n]);
        }
}

// ---------------------------------------------------------------- flash attention + q-residual
// R15-verified: 8 waves x 16 q-rows (128 q/block, grid 512), role-split staging (waves 0-3 K,
// waves 4-7 V^T), dbuf K/V, t+2 prefetch, setprio, ones-MFMA l, log2-softmax, defer-max,
// bf16 out, XCD-aware decode.
__global__ __launch_bounds__(512, 4)
void attn_kernel(const u16* __restrict__ qb, const u16* __restrict__ kb,
                 const u16* __restrict__ vb, u16* __restrict__ Ob) {
    __shared__ u16 Klds[2 * 64 * 64];
    __shared__ u16 Vtlds[2 * 64 * 64];
    __shared__ u16 Plds[8 * 16 * 64];
    const int tid = threadIdx.x;
    const int w = tid >> 6, lane = tid & 63;
    const int g = lane >> 4, lo = lane & 15;
    const int bid = blockIdx.x;
    const int xcd = bid & 7;
    const int member = (bid >> 3) & 15;
    const int grp = ((bid >> 7) << 3) | xcd;    // [0,32): (b,h) group
    const int q0 = member * 128;
    const int h = grp & 3, b = grp >> 2;
    const size_t hbase = (size_t)b * 2048 * 256 + (size_t)h * 64;

    short8 qf[2];
#pragma unroll
    for (int c = 0; c < 2; ++c) {
        const size_t row = (size_t)(q0 + w * 16 + lo);
        qf[c] = *(const short8*)&qb[hbase + row * 256 + c * 32 + g * 8];
    }
    const short8 vones = {0x3F80, 0x3F80, 0x3F80, 0x3F80, 0x3F80, 0x3F80, 0x3F80, 0x3F80};

    const f32x4 fz = {0.f, 0.f, 0.f, 0.f};
    f32x4 oacc[4];
#pragma unroll
    for (int n = 0; n < 4; ++n) oacc[n] = fz;
    f32x4 l_acc = fz;
    float m_run = -1e30f;

    char* Pb = (char*)Plds + w * 2048;

    const bool kRole = (tid < 256);
    const int skey = tid & 63, sseg = (tid >> 6) & 3;
    const int t4 = tid & 255;
    const int vkey = (t4 & 31) * 2, vd0 = (t4 >> 5) * 8;
    const u16* gbase;
    int goff2;
    if (kRole) { gbase = &kb[hbase + (size_t)skey * 256 + sseg * 16]; goff2 = 8; }
    else       { gbase = &vb[hbase + (size_t)vkey * 256 + vd0];       goff2 = 256; }

    uint4 s0, s1;
    auto load_tile = [&](int kt) {
        const u16* p = gbase + (size_t)kt * 16384;
        s0 = *(const uint4*)p;
        s1 = *(const uint4*)(p + goff2);
    };
    auto write_tile = [&](int sel) {
        if (kRole) {
            char* Kb_ = (char*)Klds + sel * 8192;
            const u32 sw = (u32)((skey & 7) << 4);
            const u32 ba = (u32)(skey * 128 + sseg * 32);
            *(uint4*)(Kb_ + ((ba) ^ sw)) = s0;
            *(uint4*)(Kb_ + ((ba + 16) ^ sw)) = s1;
        } else {
            char* Vb_ = (char*)Vtlds + sel * 8192;
            union { uint4 v; u16 hh[8]; } a0, a1;
            a0.v = s0; a1.v = s1;
#pragma unroll
            for (int i = 0; i < 8; ++i) {
                const int d = vd0 + i;
                const u32 addr = (u32)(d * 128 + vkey * 2) ^ (u32)((d & 7) << 4);
                *(u32*)(Vb_ + addr) = (u32)a0.hh[i] | ((u32)a1.hh[i] << 16);
            }
        }
    };

    load_tile(0);
    write_tile(0);
    load_tile(1);
    __syncthreads();

#pragma unroll 1
    for (int kt = 0; kt < 32; ++kt) {
        const int cur = kt & 1;
        char* Klb = (char*)Klds + cur * 8192;
        char* Vtb = (char*)Vtlds + cur * 8192;

        // QK^T (swapped)
        f32x4 sc[4];
#pragma unroll
        for (int km = 0; km < 4; ++km) sc[km] = fz;
        __builtin_amdgcn_s_setprio(1);
#pragma unroll
        for (int c = 0; c < 2; ++c)
#pragma unroll
            for (int km = 0; km < 4; ++km) {
                const int key = km * 16 + lo;
                const u32 addr = (u32)(key * 128 + c * 64 + g * 16) ^ (u32)((key & 7) << 4);
                const short8 kf = *(const short8*)(Klb + addr);
                sc[km] = __builtin_amdgcn_mfma_f32_16x16x32_bf16(kf, qf[c], sc[km], 0, 0, 0);
            }
        __builtin_amdgcn_s_setprio(0);

        // online softmax (per q = lo), deferred-max
        float mt = -1e30f;
#pragma unroll
        for (int km = 0; km < 4; ++km)
#pragma unroll
            for (int r = 0; r < 4; ++r) mt = fmaxf(mt, sc[km][r]);
        mt = fmaxf(mt, __shfl_xor(mt, 16));
        mt = fmaxf(mt, __shfl_xor(mt, 32));
        if (!__all(mt <= m_run + 11.5f)) {
            const float mnew = fmaxf(m_run, mt);
            const float alpha = __builtin_amdgcn_exp2f(m_run - mnew);
#pragma unroll
            for (int r = 0; r < 4; ++r) {
                const float a = __shfl(alpha, (lane & 48) | (g * 4 + r));
                l_acc[r] *= a;
#pragma unroll
                for (int n = 0; n < 4; ++n) oacc[n][r] *= a;
            }
            m_run = mnew;
        }
#pragma unroll
        for (int km = 0; km < 4; ++km)
#pragma unroll
            for (int r = 0; r < 4; ++r)
                sc[km][r] = __builtin_amdgcn_exp2f(sc[km][r] - m_run);

        // P^T -> P_lds
        {
            const u32 sw = (u32)((lo & 7) << 4);
#pragma unroll
            for (int km = 0; km < 4; ++km) {
                uint2 val;
                val.x = pack_bf16_fast(sc[km][0], sc[km][1]);
                val.y = pack_bf16_fast(sc[km][2], sc[km][3]);
                const u32 addr = (u32)(lo * 128 + km * 32 + g * 8) ^ sw;
                *(uint2*)(Pb + addr) = val;
            }
        }

        // PV + ones-column l
        __builtin_amdgcn_s_setprio(1);
#pragma unroll
        for (int c = 0; c < 2; ++c) {
            const u32 paddr = (u32)(lo * 128 + c * 64 + g * 16) ^ (u32)((lo & 7) << 4);
            const short8 pf = *(const short8*)(Pb + paddr);
#pragma unroll
            for (int n = 0; n < 4; ++n) {
                const int d = n * 16 + lo;
                const u32 addr = (u32)(d * 128 + c * 64 + g * 16) ^ (u32)((d & 7) << 4);
                const short8 vf = *(const short8*)(Vtb + addr);
                oacc[n] = __builtin_amdgcn_mfma_f32_16x16x32_bf16(pf, vf, oacc[n], 0, 0, 0);
            }
            l_acc = __builtin_amdgcn_mfma_f32_16x16x32_bf16(pf, vones, l_acc, 0, 0, 0);
        }
        __builtin_amdgcn_s_setprio(0);

        if (kt < 31) write_tile(cur ^ 1);
        if (kt < 30) load_tile(kt + 2);
        __syncthreads();
    }

    // finalize: O = bf16(q + oacc / l)
#pragma unroll
    for (int r = 0; r < 4; ++r) {
        const float li = 1.0f / l_acc[r];
        const size_t row = (size_t)(q0 + w * 16 + g * 4 + r);
#pragma unroll
        for (int n = 0; n < 4; ++n) {
            const int d = n * 16 + lo;
            const size_t idx = hbase + row * 256 + d;
            Ob[idx] = f2bf(oacc[n][r] * li + bf2f(qb[idx]));
        }
    }
}

// ---------------------------------------------------------------- fused tail: LN0 + MLP + LN1
// R15-verified 32-row structure. Grid 512 (2 blocks/CU), LDS 48 KB (Xs 16 KB + Bs 32 KB).
__global__ __launch_bounds__(256)
void tail_kernel(const u16* __restrict__ Ob, const u16* __restrict__ BT,
                 const float* __restrict__ bo, const float* __restrict__ g0,
                 const float* __restrict__ be0, const float* __restrict__ g1,
                 const float* __restrict__ be1, float* __restrict__ out) {
    __shared__ char lds[49152];          // Xs 16 KB @0 (row stride 512B), Bs 32 KB @16384
    char* Xs = lds;
    u16* Bs = (u16*)(lds + 16384);
    const int tid = threadIdx.x;
    const int w = tid >> 6, lane = tid & 63;
    const int g = lane >> 4, lo = lane & 15;
    const int rowB = blockIdx.x * 32;
    const int wc = w * 64;

    const int lrow = tid >> 3, lseg = tid & 7;   // 32 rows x 8 segs of 32 cols
    const u32 lsw = (u32)((lrow & 7) << 4);

    // ---------------- hoisted kt=0 Bs staging (overlaps B global-load latency with LN0)
    {
        const u16* gb = BT + (size_t)tid * 256;
        const u32 swB = (u32)((tid & 7) << 4);
        const u32 baB = (u32)(tid * 128);
#pragma unroll
        for (int j = 0; j < 8; ++j) {
            uint4 bj = *(const uint4*)(gb + j * 8);
            *(uint4*)((char*)Bs + ((baB + j * 16) ^ swB)) = bj;
        }
    }

    // ---------------- phase 0: LN0 -> Xs
    {
        const size_t grow = (size_t)(rowB + lrow);
        const u16* src = Ob + grow * 256 + lseg * 32;
        uint4 r4[4];
#pragma unroll
        for (int j = 0; j < 4; ++j) r4[j] = *(const uint4*)(src + j * 8);
        float s = 0.f, q = 0.f;
#pragma unroll
        for (int j = 0; j < 4; ++j) {
            const u32 uu[4] = {r4[j].x, r4[j].y, r4[j].z, r4[j].w};
#pragma unroll
            for (int e = 0; e < 4; ++e) {
                const float f0 = bf2f((u16)(uu[e] & 0xffff));
                const float f1 = bf2f((u16)(uu[e] >> 16));
                s += f0 + f1;
                q += f0 * f0 + f1 * f1;
            }
        }
        s += __shfl_xor(s, 1); q += __shfl_xor(q, 1);
        s += __shfl_xor(s, 2); q += __shfl_xor(q, 2);
        s += __shfl_xor(s, 4); q += __shfl_xor(q, 4);
        const float mu = s * (1.f / 256.f);
        const float var = q * (1.f / 256.f) - mu * mu;
        const float rstd = rsqrtf(var + 1e-5f);
        const float* gp = g0 + lseg * 32;
        const float* bp = be0 + lseg * 32;
#pragma unroll
        for (int j = 0; j < 4; ++j) {
            const u32 uu[4] = {r4[j].x, r4[j].y, r4[j].z, r4[j].w};
            float4 gv0 = *(const float4*)(gp + j * 8);
            float4 gv1 = *(const float4*)(gp + j * 8 + 4);
            float4 bb0 = *(const float4*)(bp + j * 8);
            float4 bb1 = *(const float4*)(bp + j * 8 + 4);
            uint4 o;
            o.x = pack_bf16((bf2f((u16)(uu[0] & 0xffff)) - mu) * rstd * gv0.x + bb0.x,
                            (bf2f((u16)(uu[0] >> 16))    - mu) * rstd * gv0.y + bb0.y);
            o.y = pack_bf16((bf2f((u16)(uu[1] & 0xffff)) - mu) * rstd * gv0.z + bb0.z,
                            (bf2f((u16)(uu[1] >> 16))    - mu) * rstd * gv0.w + bb0.w);
            o.z = pack_bf16((bf2f((u16)(uu[2] & 0xffff)) - mu) * rstd * gv1.x + bb1.x,
                            (bf2f((u16)(uu[2] >> 16))    - mu) * rstd * gv1.y + bb1.y);
            o.w = pack_bf16((bf2f((u16)(uu[3] & 0xffff)) - mu) * rstd * gv1.z + bb1.z,
                            (bf2f((u16)(uu[3] >> 16))    - mu) * rstd * gv1.w + bb1.w);
            const u32 addr = (u32)(lrow * 512 + lseg * 64 + j * 16) ^ lsw;
            *(uint4*)(Xs + addr) = o;
        }
    }
    __syncthreads();   // covers BOTH hoisted Bs-stage writes and phase-0 Xs writes

    // ---------------- GEMM: acc = X @ Wo (A from Xs; Bs staged per K-tile, kt=0 pre-staged)
    const f32x4 fz = {0.f, 0.f, 0.f, 0.f};
    f32x4 acc[2][4];
#pragma unroll
    for (int m = 0; m < 2; ++m)
#pragma unroll
        for (int n = 0; n < 4; ++n) acc[m][n] = fz;

#pragma unroll 1
    for (int kt = 0; kt < 4; ++kt) {
        if (kt) {
            __syncthreads();   // all waves done reading Bs(kt-1)
            const u16* gb = BT + (size_t)tid * 256 + kt * 64;
            const u32 swB = (u32)((tid & 7) << 4);
            const u32 baB = (u32)(tid * 128);
#pragma unroll
            for (int j = 0; j < 8; ++j) {
                uint4 bj = *(const uint4*)(gb + j * 8);
                *(uint4*)((char*)Bs + ((baB + j * 16) ^ swB)) = bj;
            }
            __syncthreads();
        }
#pragma unroll
        for (int c = 0; c < 2; ++c) {
            short8 af[2], bfr[4];
#pragma unroll
            for (int m = 0; m < 2; ++m) {
                const int row = m * 16 + lo;
                const u32 addr = (u32)(row * 512 + kt * 128 + c * 64 + g * 16) ^ (u32)((row & 7) << 4);
                af[m] = *(const short8*)(Xs + addr);
            }
#pragma unroll
            for (int n = 0; n < 4; ++n) {
                const int row = wc + n * 16 + lo;
                const u32 addr = (u32)(row * 128 + c * 64 + g * 16) ^ (u32)((row & 7) << 4);
                bfr[n] = *(const short8*)((char*)Bs + addr);
            }
#pragma unroll
            for (int m = 0; m < 2; ++m)
#pragma unroll
                for (int n = 0; n < 4; ++n)
                    acc[m][n] = __builtin_amdgcn_mfma_f32_16x16x32_bf16(af[m], bfr[n], acc[m][n], 0, 0, 0);
        }
    }

    float bv[4];
#pragma unroll
    for (int n = 0; n < 4; ++n) bv[n] = bo[wc + n * 16 + lo];

    __syncthreads();   // ALL af reads of Xs complete before y overwrites

    // ---------------- epilogue: y = X + relu(acc+bias), element-wise overwrite of Xs
#pragma unroll
    for (int m = 0; m < 2; ++m)
#pragma unroll
        for (int r = 0; r < 4; ++r) {
            const int row_l = m * 16 + g * 4 + r;
            const u32 sw = (u32)((row_l & 7) << 4);
#pragma unroll
            for (int n = 0; n < 4; ++n) {
                const int col = wc + n * 16 + lo;
                const u32 badr = (u32)(row_l * 512 + col * 2);
                char* p = Xs + ((badr & ~15u) ^ sw) + (badr & 15u);
                const float resid = bf2f(*(u16*)p);
                *(u16*)p = f2bf(resid + fmaxf(acc[m][n][r] + bv[n], 0.f));
            }
        }
    __syncthreads();

    // ---------------- phase 2: LN1 over Xs -> d_out (two passes)
    {
        const u32 rbase = (u32)(lrow * 512 + lseg * 64);
        float s = 0.f, q = 0.f;
#pragma unroll
        for (int j = 0; j < 4; ++j) {
            uint4 v4 = *(const uint4*)(Xs + ((rbase + j * 16) ^ lsw));
            const u32 uu[4] = {v4.x, v4.y, v4.z, v4.w};
#pragma unroll
            for (int e = 0; e < 4; ++e) {
                const float f0 = bf2f((u16)(uu[e] & 0xffff));
                const float f1 = bf2f((u16)(uu[e] >> 16));
                s += f0 + f1;
                q += f0 * f0 + f1 * f1;
            }
        }
        s += __shfl_xor(s, 1); q += __shfl_xor(q, 1);
        s += __shfl_xor(s, 2); q += __shfl_xor(q, 2);
        s += __shfl_xor(s, 4); q += __shfl_xor(q, 4);
        const float mu = s * (1.f / 256.f);
        const float var = q * (1.f / 256.f) - mu * mu;
        const float rstd = rsqrtf(var + 1e-5f);
        const size_t grow = (size_t)(rowB + lrow);
        float* op = out + grow * 256 + lseg * 32;
        const float* gp = g1 + lseg * 32;
        const float* bp = be1 + lseg * 32;
#pragma unroll
        for (int j = 0; j < 4; ++j) {
            uint4 v4 = *(const uint4*)(Xs + ((rbase + j * 16) ^ lsw));
            const u32 uu[4] = {v4.x, v4.y, v4.z, v4.w};
#pragma unroll
            for (int e = 0; e < 2; ++e) {
                float4 gv = *(const float4*)(gp + j * 8 + e * 4);
                float4 bb = *(const float4*)(bp + j * 8 + e * 4);
                float4 o4;
                o4.x = (bf2f((u16)(uu[e * 2]     & 0xffff)) - mu) * rstd * gv.x + bb.x;
                o4.y = (bf2f((u16)(uu[e * 2]     >> 16))    - mu) * rstd * gv.y + bb.y;
                o4.z = (bf2f((u16)(uu[e * 2 + 1] & 0xffff)) - mu) * rstd * gv.z + bb.z;
                o4.w = (bf2f((u16)(uu[e * 2 + 1] >> 16))    - mu) * rstd * gv.w + bb.w;
                *(float4*)(op + j * 8 + e * 4) = o4;
            }
        }
    }
}

// ----------------------------------------------------------------------------------------------
// Workspace: qb 8MB | kbuf 8MB | vbuf 8MB | WT 0.5MB | bks | Ob16 8MB — ~32.75MB. 4 launches.
extern "C" void kernel_launch(void* const* d_in, const int* in_sizes, int n_in,
                              void* d_out, int out_size, void* d_ws, size_t ws_size,
                              hipStream_t stream) {
    const float* Q  = (const float*)d_in[0];
    const float* K  = (const float*)d_in[1];
    const float* Wq = (const float*)d_in[2];
    const float* bq = (const float*)d_in[3];
    const float* Wk = (const float*)d_in[4];
    const float* bk = (const float*)d_in[5];
    const float* Wv = (const float*)d_in[6];
    const float* bv = (const float*)d_in[7];
    const float* Wo = (const float*)d_in[8];
    const float* bo = (const float*)d_in[9];
    const float* g0 = (const float*)d_in[10];
    const float* be0 = (const float*)d_in[11];
    const float* g1 = (const float*)d_in[12];
    const float* be1 = (const float*)d_in[13];
    float* out = (float*)d_out;

    const size_t NE = (size_t)8 * 2048 * 256;  // 4,194,304
    char* ws = (char*)d_ws;
    size_t off = 0;
    auto alloc = [&](size_t bytes) { char* p = ws + off; off += (bytes + 255) & ~(size_t)255; return p; };
    u16* qb   = (u16*)alloc(NE * 2);
    u16* kbuf = (u16*)alloc(NE * 2);
    u16* vbuf = (u16*)alloc(NE * 2);
    u16* WT   = (u16*)alloc(4 * 65536 * 2);
    float* bks = (float*)alloc(256 * 4);
    u16* Ob16 = (u16*)alloc(NE * 2);

    wt_kernel<<<dim3(256, 4), 256, 0, stream>>>(Wq, Wk, Wv, Wo, bk, WT, bks);

    proj_kernel<<<dim3(256, 3), 256, 0, stream>>>(Q, K, WT, bq, bks, bv, qb, kbuf, vbuf);

    attn_kernel<<<512, 512, 0, stream>>>(qb, kbuf, vbuf, Ob16);

    tail_kernel<<<512, 256, 0, stream>>>(Ob16, WT + 3 * 65536, bo, g0, be0, g1, be1, out);
}